// Round 1
// baseline (6208.180 us; speedup 1.0000x reference)
//
#include <hip/hip_runtime.h>
#include <math.h>

#define N_NODES 100000
#define N_EDGES 1600000
#define EN_TOT  (N_EDGES + N_NODES)
#define BATCH   16
#define EDGE_DIM 16
#define NEG_SLOPE 0.2f

// ---------- helpers ----------
__device__ __forceinline__ unsigned fenc(float x) {
    unsigned b = __float_as_uint(x);
    return (b & 0x80000000u) ? ~b : (b | 0x80000000u);
}
__device__ __forceinline__ float fdec(unsigned u) {
    return __uint_as_float((u & 0x80000000u) ? (u & 0x7FFFFFFFu) : ~u);
}

// ---------- kernels ----------
__global__ void zero_kernel(float* __restrict__ p, long long n) {
    long long i = (long long)blockIdx.x * blockDim.x + threadIdx.x;
    long long stride = (long long)gridDim.x * blockDim.x;
    for (; i < n; i += stride) p[i] = 0.0f;
}

// accumulate per-dst sums of edge_attr and counts
__global__ void loopattr_accum(const int* __restrict__ dst, const float* __restrict__ ea,
                               float* __restrict__ lsum, float* __restrict__ cnt) {
    long long t = (long long)blockIdx.x * blockDim.x + threadIdx.x;
    long long total = (long long)N_EDGES * EDGE_DIM;
    if (t >= total) return;
    int e = (int)(t >> 4);
    int k = (int)(t & 15);
    int d = dst[e];
    atomicAdd(&lsum[(long long)d * EDGE_DIM + k], ea[t]);
    if (k == 0) atomicAdd(&cnt[d], 1.0f);
}

__global__ void loopattr_fin(float* __restrict__ lsum, const float* __restrict__ cnt) {
    long long t = (long long)blockIdx.x * blockDim.x + threadIdx.x;
    if (t >= (long long)N_NODES * EDGE_DIM) return;
    lsum[t] = lsum[t] / fmaxf(cnt[t >> 4], 1.0f);
}

// out_l = in @ Wl.T + bl ; out_r = in @ Wr.T + br   (W: [128,K])
// block = 256 threads: t<128 -> Wl column t, t>=128 -> Wr column t-128
template<int K>
__global__ __launch_bounds__(256) void dual_linear(
    const float* __restrict__ in,
    const float* __restrict__ Wl, const float* __restrict__ bl,
    const float* __restrict__ Wr, const float* __restrict__ br,
    float* __restrict__ outl, float* __restrict__ outr, int N)
{
    constexpr int ROWS = 32;
    __shared__ float srow[ROWS][K];
    int t = threadIdx.x;
    int base = blockIdx.x * ROWS;
    for (int i = t; i < ROWS * K; i += 256) {
        int r = i / K, k = i - r * K;
        int n = base + r;
        srow[r][k] = (n < N) ? in[(long long)n * K + k] : 0.0f;
    }
    __syncthreads();
    const float* W  = (t < 128) ? Wl : Wr;
    const float* bb = (t < 128) ? bl : br;
    float* outp     = (t < 128) ? outl : outr;
    int j = t & 127;
    float bj = bb[j];
    float acc[ROWS];
#pragma unroll
    for (int r = 0; r < ROWS; ++r) acc[r] = bj;
    for (int k = 0; k < K; ++k) {
        float w = W[j * K + k];
#pragma unroll
        for (int r = 0; r < ROWS; ++r) acc[r] += srow[r][k] * w;
    }
    for (int r = 0; r < ROWS; ++r) {
        int n = base + r;
        if (n < N) outp[(long long)n * 128 + j] = acc[r];
    }
}

// per-edge GATv2 logit + segment max (2 edges per 256-thread block, 128 thr/edge)
__global__ __launch_bounds__(256) void edge_logits(
    const int* __restrict__ src, const int* __restrict__ dst,
    const float* __restrict__ ea, const float* __restrict__ lattr,
    const float* __restrict__ We, const float* __restrict__ att,
    const float* __restrict__ xl, const float* __restrict__ xr,
    float* __restrict__ logits, unsigned int* __restrict__ mx)
{
    __shared__ float sWe[128 * EDGE_DIM];
    __shared__ float satt[128];
    int t = threadIdx.x;
    for (int i = t; i < 128 * EDGE_DIM; i += 256) sWe[i] = We[i];
    if (t < 128) satt[t] = att[t];
    __syncthreads();
    long long e = (long long)blockIdx.x * 2 + (t >> 7);
    if (e >= EN_TOT) return;
    int c = t & 127;
    int s, d; const float* attr;
    if (e < N_EDGES) { s = src[e]; d = dst[e]; attr = ea + e * EDGE_DIM; }
    else { int n = (int)(e - N_EDGES); s = n; d = n; attr = lattr + (long long)n * EDGE_DIM; }
    float eec = 0.0f;
#pragma unroll
    for (int k = 0; k < EDGE_DIM; ++k) eec += attr[k] * sWe[c * EDGE_DIM + k];
    float m = xl[(long long)s * 128 + c] + xr[(long long)d * 128 + c] + eec;
    m = (m > 0.0f) ? m : NEG_SLOPE * m;
    float prod = m * satt[c];
#pragma unroll
    for (int off = 16; off; off >>= 1) prod += __shfl_xor(prod, off, 32);
    if ((c & 31) == 0) {
        int h = c >> 5;
        logits[e * 4 + h] = prod;
        atomicMax(&mx[(long long)d * 4 + h], fenc(prod));
    }
}

// ex = exp(logit - max); accumulate denominators
__global__ void exp_den(const int* __restrict__ dst, float* __restrict__ logits,
                        const unsigned int* __restrict__ mx, float* __restrict__ den) {
    long long t = (long long)blockIdx.x * blockDim.x + threadIdx.x;
    if (t >= (long long)EN_TOT * 4) return;
    long long e = t >> 2;
    int h = (int)(t & 3);
    int d = (e < N_EDGES) ? dst[e] : (int)(e - N_EDGES);
    float l = logits[t];
    float ex = expf(l - fdec(mx[(long long)d * 4 + h]));
    logits[t] = ex;
    atomicAdd(&den[(long long)d * 4 + h], ex);
}

// y[d] += alpha * xl[s]
__global__ __launch_bounds__(256) void aggregate(
    const int* __restrict__ src, const int* __restrict__ dst,
    const float* __restrict__ logits, const float* __restrict__ den,
    const float* __restrict__ xl, float* __restrict__ y)
{
    long long e = (long long)blockIdx.x * 2 + (threadIdx.x >> 7);
    if (e >= EN_TOT) return;
    int c = threadIdx.x & 127;
    int s, d;
    if (e < N_EDGES) { s = src[e]; d = dst[e]; }
    else { s = d = (int)(e - N_EDGES); }
    int h = c >> 5;
    float alpha = logits[e * 4 + h] / den[(long long)d * 4 + h];
    atomicAdd(&y[(long long)d * 128 + c], alpha * xl[(long long)s * 128 + c]);
}

__global__ void finalize_nodes(float* __restrict__ y, const float* __restrict__ bias, int do_elu) {
    long long t = (long long)blockIdx.x * blockDim.x + threadIdx.x;
    if (t >= (long long)N_NODES * 128) return;
    int c = (int)(t & 127);
    float v = y[t] + bias[c];
    if (do_elu) v = (v > 0.0f) ? v : (expf(v) - 1.0f);
    y[t] = v;
}

__global__ void pool_kernel(const float* __restrict__ y, const int* __restrict__ batch,
                            float* __restrict__ gsum, float* __restrict__ gcnt) {
    long long t = (long long)blockIdx.x * blockDim.x + threadIdx.x;
    if (t >= (long long)N_NODES * 128) return;
    int n = (int)(t >> 7);
    int c = (int)(t & 127);
    int b = batch[n];
    atomicAdd(&gsum[b * 128 + c], y[t]);
    if (c == 0) atomicAdd(&gcnt[b], 1.0f);
}

__global__ __launch_bounds__(128) void head_kernel(
    const float* __restrict__ gsum, const float* __restrict__ gcnt,
    const float* __restrict__ Wg1, const float* __restrict__ bg1,
    const float* __restrict__ Wg2, const float* __restrict__ bg2,
    const float* __restrict__ Wp, const float* __restrict__ bp,
    float* __restrict__ out)
{
    int b = blockIdx.x;
    int j = threadIdx.x;
    __shared__ float g[128], h[128];
    float cntv = fmaxf(gcnt[b], 1.0f);
    g[j] = gsum[b * 128 + j] / cntv;
    __syncthreads();
    float a = bg1[j];
    for (int k = 0; k < 128; ++k) a += g[k] * Wg1[j * 128 + k];
    h[j] = fmaxf(a, 0.0f);
    __syncthreads();
    if (j < 15) {
        float o = bg2[j];
        for (int k = 0; k < 128; ++k) o += h[k] * Wg2[j * 128 + k];
        out[b * 25 + j] = o;
    }
    if (j >= 64 && j < 74) {
        int p = j - 64;
        float o = bp[p];
        for (int k = 0; k < 128; ++k) o += g[k] * Wp[p * 128 + k];
        out[b * 25 + 15 + p] = o;
    }
}

// ---------- launch ----------
extern "C" void kernel_launch(void* const* d_in, const int* in_sizes, int n_in,
                              void* d_out, int out_size, void* d_ws, size_t ws_size,
                              hipStream_t stream)
{
    const float* x     = (const float*)d_in[0];
    const int*   ei    = (const int*)  d_in[1];
    const float* ea    = (const float*)d_in[2];
    const int*   batch = (const int*)  d_in[3];
    const float* W1l = (const float*)d_in[4],  *b1l  = (const float*)d_in[5];
    const float* W1r = (const float*)d_in[6],  *b1r  = (const float*)d_in[7];
    const float* W1e = (const float*)d_in[8],  *att1 = (const float*)d_in[9];
    const float* bias1 = (const float*)d_in[10];
    const float* W2l = (const float*)d_in[11], *b2l  = (const float*)d_in[12];
    const float* W2r = (const float*)d_in[13], *b2r  = (const float*)d_in[14];
    const float* W2e = (const float*)d_in[15], *att2 = (const float*)d_in[16];
    const float* bias2 = (const float*)d_in[17];
    const float* Wg1 = (const float*)d_in[18], *bg1 = (const float*)d_in[19];
    const float* Wg2 = (const float*)d_in[20], *bg2 = (const float*)d_in[21];
    const float* Wp  = (const float*)d_in[22], *bp  = (const float*)d_in[23];
    const int* src = ei;
    const int* dst = ei + N_EDGES;

    float* ws = (float*)d_ws;
    float* xl     = ws;
    float* xr     = xl + (size_t)N_NODES * 128;
    float* y      = xr + (size_t)N_NODES * 128;
    float* logits = y  + (size_t)N_NODES * 128;
    float* lattr  = logits + (size_t)EN_TOT * 4;
    float* cnt    = lattr + (size_t)N_NODES * EDGE_DIM;
    unsigned* mx  = (unsigned*)(cnt + N_NODES);
    float* den    = (float*)mx + (size_t)N_NODES * 4;
    float* gsum   = den + (size_t)N_NODES * 4;
    float* gcnt   = gsum + BATCH * 128;

    float* out = (float*)d_out;

    // zero lattr, cnt, mx, den, gsum, gcnt (contiguous)
    long long zinit = (long long)N_NODES * EDGE_DIM + N_NODES + (long long)N_NODES * 8
                      + BATCH * 128 + BATCH;
    zero_kernel<<<2048, 256, 0, stream>>>(lattr, zinit);

    // self-loop attrs (shared by both layers)
    {
        long long total = (long long)N_EDGES * EDGE_DIM;
        int blocks = (int)((total + 255) / 256);
        loopattr_accum<<<blocks, 256, 0, stream>>>(dst, ea, lattr, cnt);
        loopattr_fin<<<(N_NODES * EDGE_DIM + 255) / 256, 256, 0, stream>>>(lattr, cnt);
    }

    const int EBLK = (int)((EN_TOT + 1) / 2);
    const int EH_BLK = (int)(((long long)EN_TOT * 4 + 255) / 256);
    const int NODE_BLK = (int)(((long long)N_NODES * 128 + 255) / 256);

    // ---- layer 1 ----
    dual_linear<32><<<(N_NODES + 31) / 32, 256, 0, stream>>>(x, W1l, b1l, W1r, b1r, xl, xr, N_NODES);
    zero_kernel<<<2048, 256, 0, stream>>>(y, (long long)N_NODES * 128);
    edge_logits<<<EBLK, 256, 0, stream>>>(src, dst, ea, lattr, W1e, att1, xl, xr, logits, mx);
    exp_den<<<EH_BLK, 256, 0, stream>>>(dst, logits, mx, den);
    aggregate<<<EBLK, 256, 0, stream>>>(src, dst, logits, den, xl, y);
    finalize_nodes<<<NODE_BLK, 256, 0, stream>>>(y, bias1, 1);

    // ---- layer 2 ----
    dual_linear<128><<<(N_NODES + 31) / 32, 256, 0, stream>>>(y, W2l, b2l, W2r, b2r, xl, xr, N_NODES);
    zero_kernel<<<2048, 256, 0, stream>>>(y, (long long)N_NODES * 128);
    zero_kernel<<<2048, 256, 0, stream>>>((float*)mx, (long long)N_NODES * 8); // mx + den
    edge_logits<<<EBLK, 256, 0, stream>>>(src, dst, ea, lattr, W2e, att2, xl, xr, logits, mx);
    exp_den<<<EH_BLK, 256, 0, stream>>>(dst, logits, mx, den);
    aggregate<<<EBLK, 256, 0, stream>>>(src, dst, logits, den, xl, y);
    finalize_nodes<<<NODE_BLK, 256, 0, stream>>>(y, bias2, 0);

    // ---- pool + head ----
    pool_kernel<<<NODE_BLK, 256, 0, stream>>>(y, batch, gsum, gcnt);
    head_kernel<<<BATCH, 128, 0, stream>>>(gsum, gcnt, Wg1, bg1, Wg2, bg2, Wp, bp, out);
}

// Round 2
// 2879.812 us; speedup vs baseline: 2.1558x; 2.1558x over previous
//
#include <hip/hip_runtime.h>
#include <math.h>

#define N_NODES 100000
#define N_EDGES 1600000
#define EN_TOT  (N_EDGES + N_NODES)
#define BATCH   16
#define EDGE_DIM 16
#define NEG_SLOPE 0.2f
#define NB_SCAN 391   // ceil(N_NODES/256)

// ---------------- utility ----------------
__global__ void zero_kernel(float* __restrict__ p, long long n) {
    long long i = (long long)blockIdx.x * blockDim.x + threadIdx.x;
    long long stride = (long long)gridDim.x * blockDim.x;
    for (; i < n; i += stride) p[i] = 0.0f;
}

// ---------------- CSR build ----------------
__global__ void count_deg(const int* __restrict__ dst, int* __restrict__ deg) {
    int e = blockIdx.x * 256 + threadIdx.x;
    if (e < N_EDGES) atomicAdd(&deg[dst[e]], 1);
}

// inclusive scan of (deg[n]+1) within 256-blocks; incl -> tmp, block total -> bsum
__global__ __launch_bounds__(256) void scan1(const int* __restrict__ deg,
                                             int* __restrict__ incl, int* __restrict__ bsum) {
    __shared__ int s[256];
    int n = blockIdx.x * 256 + threadIdx.x;
    int v = (n < N_NODES) ? deg[n] + 1 : 0;
    s[threadIdx.x] = v;
    __syncthreads();
    for (int off = 1; off < 256; off <<= 1) {
        int t = (threadIdx.x >= off) ? s[threadIdx.x - off] : 0;
        __syncthreads();
        s[threadIdx.x] += t;
        __syncthreads();
    }
    if (n < N_NODES) incl[n] = s[threadIdx.x];
    if (threadIdx.x == 255) bsum[blockIdx.x] = s[255];
}

__global__ __launch_bounds__(512) void scan2(int* __restrict__ bsum) {
    __shared__ int s[512];
    int t = threadIdx.x;
    int v = (t < NB_SCAN) ? bsum[t] : 0;
    s[t] = v;
    __syncthreads();
    for (int off = 1; off < 512; off <<= 1) {
        int u = (t >= off) ? s[t - off] : 0;
        __syncthreads();
        s[t] += u;
        __syncthreads();
    }
    if (t < NB_SCAN) bsum[t] = s[t] - v;  // exclusive block prefix
}

__global__ void scan3(const int* __restrict__ incl, const int* __restrict__ deg,
                      const int* __restrict__ bsum, int* __restrict__ offs) {
    int n = blockIdx.x * 256 + threadIdx.x;
    if (n < N_NODES) offs[n] = incl[n] - (deg[n] + 1) + bsum[blockIdx.x];
    if (n == 0) offs[N_NODES] = EN_TOT;
}

// scatter edges into CSR slots; self-loop goes in the LAST slot of each row
__global__ void scatter(const int* __restrict__ src, const int* __restrict__ dst,
                        const int* __restrict__ offs, int* __restrict__ cursor,
                        int* __restrict__ csr_src, int* __restrict__ csr_eid) {
    int e = blockIdx.x * 256 + threadIdx.x;
    if (e < N_EDGES) {
        int d = dst[e];
        int r = atomicAdd(&cursor[d], 1);
        int pos = offs[d] + r;
        csr_src[pos] = src[e];
        csr_eid[pos] = e;
    } else if (e < EN_TOT) {
        int n = e - N_EDGES;
        int pos = offs[n + 1] - 1;
        csr_src[pos] = n;
        csr_eid[pos] = N_EDGES + n;  // marker: self-loop
    }
}

// per-node mean of incoming edge attrs (self-loop attr), CSR-driven, no atomics
__global__ __launch_bounds__(256) void loopattr_csr(const int* __restrict__ offs,
                                                    const int* __restrict__ csr_eid,
                                                    const float* __restrict__ ea,
                                                    float* __restrict__ lattr) {
    int node = blockIdx.x * 4 + (threadIdx.x >> 6);
    if (node >= N_NODES) return;
    int lane = threadIdx.x & 63;
    int row = offs[node];
    int degn = offs[node + 1] - 1 - row;  // real edges only
    int k = lane & 15, grp = lane >> 4;
    float acc = 0.0f;
    for (int i = grp; i < degn; i += 4) {
        int eid = csr_eid[row + i];
        acc += ea[(long long)eid * EDGE_DIM + k];
    }
    acc += __shfl_xor(acc, 16);
    acc += __shfl_xor(acc, 32);
    if (lane < 16) lattr[(long long)node * EDGE_DIM + k] = acc / fmaxf((float)degn, 1.0f);
}

// ---------------- dense transforms ----------------
// out_l = in @ Wl.T + bl ; out_r = in @ Wr.T + br   (W: [128,K])
template<int K>
__global__ __launch_bounds__(256) void dual_linear(
    const float* __restrict__ in,
    const float* __restrict__ Wl, const float* __restrict__ bl,
    const float* __restrict__ Wr, const float* __restrict__ br,
    float* __restrict__ outl, float* __restrict__ outr, int N)
{
    constexpr int ROWS = 32;
    __shared__ float srow[ROWS][K];
    int t = threadIdx.x;
    int base = blockIdx.x * ROWS;
    for (int i = t; i < ROWS * K; i += 256) {
        int r = i / K, k = i - r * K;
        int n = base + r;
        srow[r][k] = (n < N) ? in[(long long)n * K + k] : 0.0f;
    }
    __syncthreads();
    const float* W  = (t < 128) ? Wl : Wr;
    const float* bb = (t < 128) ? bl : br;
    float* outp     = (t < 128) ? outl : outr;
    int j = t & 127;
    float bj = bb[j];
    float acc[ROWS];
#pragma unroll
    for (int r = 0; r < ROWS; ++r) acc[r] = bj;
    for (int k = 0; k < K; ++k) {
        float w = W[j * K + k];
#pragma unroll
        for (int r = 0; r < ROWS; ++r) acc[r] += srow[r][k] * w;
    }
    for (int r = 0; r < ROWS; ++r) {
        int n = base + r;
        if (n < N) outp[(long long)n * 128 + j] = acc[r];
    }
}

// ---------------- fused GATv2 (logits + online softmax + aggregation + bias [+ELU]) ----------------
// one wave per node; lane owns channels c0=lane, c1=lane+64
template<int DO_ELU>
__global__ __launch_bounds__(256) void gat_fused(
    const int* __restrict__ offs, const int* __restrict__ csr_src,
    const int* __restrict__ csr_eid,
    const float* __restrict__ ea, const float* __restrict__ lattr,
    const float* __restrict__ We, const float* __restrict__ att,
    const float* __restrict__ xl, const float* __restrict__ xr,
    const float* __restrict__ bias, float* __restrict__ y)
{
    int node = blockIdx.x * 4 + (threadIdx.x >> 6);
    if (node >= N_NODES) return;
    int lane = threadIdx.x & 63;
    int c0 = lane, c1 = lane + 64;

    float we0[EDGE_DIM], we1[EDGE_DIM];
#pragma unroll
    for (int k = 0; k < EDGE_DIM; ++k) {
        we0[k] = We[c0 * EDGE_DIM + k];
        we1[k] = We[c1 * EDGE_DIM + k];
    }
    float att0 = att[c0], att1 = att[c1];

    int row = offs[node], rend = offs[node + 1];
    float xr0 = xr[(long long)node * 128 + c0];
    float xr1 = xr[(long long)node * 128 + c1];

    float m0 = -INFINITY, m1 = -INFINITY;
    float d0 = 0.0f, d1 = 0.0f, acc0 = 0.0f, acc1 = 0.0f;

    // 1-deep prefetch of the csr entries to break the csr->gather latency chain
    int s_nxt = csr_src[row];
    int e_nxt = csr_eid[row];
    for (int i = row; i < rend; ++i) {
        int s = s_nxt, eid = e_nxt;
        if (i + 1 < rend) { s_nxt = csr_src[i + 1]; e_nxt = csr_eid[i + 1]; }

        const float* ap = (eid < N_EDGES) ? ea + (long long)eid * EDGE_DIM
                                          : lattr + (long long)(eid - N_EDGES) * EDGE_DIM;
        float av = (lane < EDGE_DIM) ? ap[lane] : 0.0f;
        float xls0 = xl[(long long)s * 128 + c0];
        float xls1 = xl[(long long)s * 128 + c1];

        float e0 = 0.0f, e1 = 0.0f;
#pragma unroll
        for (int k = 0; k < EDGE_DIM; ++k) {
            float ak = __shfl(av, k);
            e0 += ak * we0[k];
            e1 += ak * we1[k];
        }
        float v0 = xls0 + xr0 + e0, v1 = xls1 + xr1 + e1;
        v0 = (v0 > 0.0f) ? v0 : NEG_SLOPE * v0;
        v1 = (v1 > 0.0f) ? v1 : NEG_SLOPE * v1;
        float p0 = v0 * att0, p1 = v1 * att1;
#pragma unroll
        for (int off = 1; off <= 16; off <<= 1) {
            p0 += __shfl_xor(p0, off);
            p1 += __shfl_xor(p1, off);
        }
        // online softmax, stream 0 (head = lane>>5), stream 1 (head = 2 + (lane>>5))
        if (p0 > m0) { float r = __expf(m0 - p0); d0 *= r; acc0 *= r; m0 = p0; }
        float w0 = __expf(p0 - m0); d0 += w0; acc0 += w0 * xls0;
        if (p1 > m1) { float r = __expf(m1 - p1); d1 *= r; acc1 *= r; m1 = p1; }
        float w1 = __expf(p1 - m1); d1 += w1; acc1 += w1 * xls1;
    }

    float o0 = acc0 / d0 + bias[c0];
    float o1 = acc1 / d1 + bias[c1];
    if (DO_ELU) {
        o0 = (o0 > 0.0f) ? o0 : (__expf(o0) - 1.0f);
        o1 = (o1 > 0.0f) ? o1 : (__expf(o1) - 1.0f);
    }
    y[(long long)node * 128 + c0] = o0;
    y[(long long)node * 128 + c1] = o1;
}

// ---------------- pool + head ----------------
__global__ void pool_kernel(const float* __restrict__ y, const int* __restrict__ batch,
                            float* __restrict__ gsum, float* __restrict__ gcnt) {
    long long t = (long long)blockIdx.x * blockDim.x + threadIdx.x;
    if (t >= (long long)N_NODES * 128) return;
    int n = (int)(t >> 7);
    int c = (int)(t & 127);
    int b = batch[n];
    atomicAdd(&gsum[b * 128 + c], y[t]);
    if (c == 0) atomicAdd(&gcnt[b], 1.0f);
}

__global__ __launch_bounds__(128) void head_kernel(
    const float* __restrict__ gsum, const float* __restrict__ gcnt,
    const float* __restrict__ Wg1, const float* __restrict__ bg1,
    const float* __restrict__ Wg2, const float* __restrict__ bg2,
    const float* __restrict__ Wp, const float* __restrict__ bp,
    float* __restrict__ out)
{
    int b = blockIdx.x;
    int j = threadIdx.x;
    __shared__ float g[128], h[128];
    float cntv = fmaxf(gcnt[b], 1.0f);
    g[j] = gsum[b * 128 + j] / cntv;
    __syncthreads();
    float a = bg1[j];
    for (int k = 0; k < 128; ++k) a += g[k] * Wg1[j * 128 + k];
    h[j] = fmaxf(a, 0.0f);
    __syncthreads();
    if (j < 15) {
        float o = bg2[j];
        for (int k = 0; k < 128; ++k) o += h[k] * Wg2[j * 128 + k];
        out[b * 25 + j] = o;
    }
    if (j >= 64 && j < 74) {
        int p = j - 64;
        float o = bp[p];
        for (int k = 0; k < 128; ++k) o += g[k] * Wp[p * 128 + k];
        out[b * 25 + 15 + p] = o;
    }
}

// ---------------- launch ----------------
extern "C" void kernel_launch(void* const* d_in, const int* in_sizes, int n_in,
                              void* d_out, int out_size, void* d_ws, size_t ws_size,
                              hipStream_t stream)
{
    const float* x     = (const float*)d_in[0];
    const int*   ei    = (const int*)  d_in[1];
    const float* ea    = (const float*)d_in[2];
    const int*   batch = (const int*)  d_in[3];
    const float* W1l = (const float*)d_in[4],  *b1l  = (const float*)d_in[5];
    const float* W1r = (const float*)d_in[6],  *b1r  = (const float*)d_in[7];
    const float* W1e = (const float*)d_in[8],  *att1 = (const float*)d_in[9];
    const float* bias1 = (const float*)d_in[10];
    const float* W2l = (const float*)d_in[11], *b2l  = (const float*)d_in[12];
    const float* W2r = (const float*)d_in[13], *b2r  = (const float*)d_in[14];
    const float* W2e = (const float*)d_in[15], *att2 = (const float*)d_in[16];
    const float* bias2 = (const float*)d_in[17];
    const float* Wg1 = (const float*)d_in[18], *bg1 = (const float*)d_in[19];
    const float* Wg2 = (const float*)d_in[20], *bg2 = (const float*)d_in[21];
    const float* Wp  = (const float*)d_in[22], *bp  = (const float*)d_in[23];
    const int* src = ei;
    const int* dst = ei + N_EDGES;

    // workspace layout (float units)
    float* ws = (float*)d_ws;
    size_t o = 0;
    float* xl    = ws + o; o += (size_t)N_NODES * 128;
    float* xr    = ws + o; o += (size_t)N_NODES * 128;
    float* y     = ws + o; o += (size_t)N_NODES * 128;
    float* lattr = ws + o; o += (size_t)N_NODES * EDGE_DIM;
    int* csr_src = (int*)(ws + o); o += (size_t)EN_TOT;
    int* csr_eid = (int*)(ws + o); o += (size_t)EN_TOT;
    int* offs    = (int*)(ws + o); o += (size_t)N_NODES + 1;
    int* deg     = (int*)(ws + o); o += (size_t)N_NODES;          // start of zero region
    int* cursor  = (int*)(ws + o); o += (size_t)N_NODES;
    float* gsum  = ws + o; o += (size_t)BATCH * 128;
    float* gcnt  = ws + o; o += (size_t)BATCH;                     // end of zero region
    int* bsum    = (int*)(ws + o); o += 512;
    int* incl    = (int*)y;  // scan temp, dead before y is written

    float* out = (float*)d_out;

    // zero deg, cursor, gsum, gcnt (contiguous)
    long long nz = (long long)N_NODES * 2 + BATCH * 128 + BATCH;
    zero_kernel<<<512, 256, 0, stream>>>((float*)deg, nz);

    // ---- CSR build (shared by both layers) ----
    count_deg<<<(N_EDGES + 255) / 256, 256, 0, stream>>>(dst, deg);
    scan1<<<NB_SCAN, 256, 0, stream>>>(deg, incl, bsum);
    scan2<<<1, 512, 0, stream>>>(bsum);
    scan3<<<NB_SCAN, 256, 0, stream>>>(incl, deg, bsum, offs);
    scatter<<<(EN_TOT + 255) / 256, 256, 0, stream>>>(src, dst, offs, cursor, csr_src, csr_eid);
    loopattr_csr<<<(N_NODES + 3) / 4, 256, 0, stream>>>(offs, csr_eid, ea, lattr);

    const int GAT_BLK = (N_NODES + 3) / 4;

    // ---- layer 1 ----
    dual_linear<32><<<(N_NODES + 31) / 32, 256, 0, stream>>>(x, W1l, b1l, W1r, b1r, xl, xr, N_NODES);
    gat_fused<1><<<GAT_BLK, 256, 0, stream>>>(offs, csr_src, csr_eid, ea, lattr,
                                              W1e, att1, xl, xr, bias1, y);

    // ---- layer 2 ----
    dual_linear<128><<<(N_NODES + 31) / 32, 256, 0, stream>>>(y, W2l, b2l, W2r, b2r, xl, xr, N_NODES);
    gat_fused<0><<<GAT_BLK, 256, 0, stream>>>(offs, csr_src, csr_eid, ea, lattr,
                                              W2e, att2, xl, xr, bias2, y);

    // ---- pool + head ----
    pool_kernel<<<(N_NODES * 128 + 255) / 256, 256, 0, stream>>>(y, batch, gsum, gcnt);
    head_kernel<<<BATCH, 128, 0, stream>>>(gsum, gcnt, Wg1, bg1, Wg2, bg2, Wp, bp, out);
}

// Round 3
// 1532.349 us; speedup vs baseline: 4.0514x; 1.8793x over previous
//
#include <hip/hip_runtime.h>
#include <math.h>

#define N_NODES 100000
#define N_EDGES 1600000
#define EN_TOT  (N_EDGES + N_NODES)
#define BATCH   16
#define EDGE_DIM 16
#define NEG_SLOPE 0.2f
#define NB_SCAN 391   // ceil(N_NODES/256)

// ---------------- utility ----------------
__global__ void zero_kernel(float* __restrict__ p, long long n) {
    long long i = (long long)blockIdx.x * blockDim.x + threadIdx.x;
    long long stride = (long long)gridDim.x * blockDim.x;
    for (; i < n; i += stride) p[i] = 0.0f;
}

// ---------------- CSR build ----------------
__global__ void count_deg(const int* __restrict__ dst, int* __restrict__ deg) {
    int e = blockIdx.x * 256 + threadIdx.x;
    if (e < N_EDGES) atomicAdd(&deg[dst[e]], 1);
}

// inclusive scan of (deg[n]+1) within 256-blocks; incl -> tmp, block total -> bsum
__global__ __launch_bounds__(256) void scan1(const int* __restrict__ deg,
                                             int* __restrict__ incl, int* __restrict__ bsum) {
    __shared__ int s[256];
    int n = blockIdx.x * 256 + threadIdx.x;
    int v = (n < N_NODES) ? deg[n] + 1 : 0;
    s[threadIdx.x] = v;
    __syncthreads();
    for (int off = 1; off < 256; off <<= 1) {
        int t = (threadIdx.x >= off) ? s[threadIdx.x - off] : 0;
        __syncthreads();
        s[threadIdx.x] += t;
        __syncthreads();
    }
    if (n < N_NODES) incl[n] = s[threadIdx.x];
    if (threadIdx.x == 255) bsum[blockIdx.x] = s[255];
}

__global__ __launch_bounds__(512) void scan2(int* __restrict__ bsum) {
    __shared__ int s[512];
    int t = threadIdx.x;
    int v = (t < NB_SCAN) ? bsum[t] : 0;
    s[t] = v;
    __syncthreads();
    for (int off = 1; off < 512; off <<= 1) {
        int u = (t >= off) ? s[t - off] : 0;
        __syncthreads();
        s[t] += u;
        __syncthreads();
    }
    if (t < NB_SCAN) bsum[t] = s[t] - v;  // exclusive block prefix
}

__global__ void scan3(const int* __restrict__ incl, const int* __restrict__ deg,
                      const int* __restrict__ bsum, int* __restrict__ offs) {
    int n = blockIdx.x * 256 + threadIdx.x;
    if (n < N_NODES) offs[n] = incl[n] - (deg[n] + 1) + bsum[blockIdx.x];
    if (n == 0) offs[N_NODES] = EN_TOT;
}

// scatter edges into CSR slots; self-loop goes in the LAST slot of each row
__global__ void scatter(const int* __restrict__ src, const int* __restrict__ dst,
                        const int* __restrict__ offs, int* __restrict__ cursor,
                        int* __restrict__ csr_src, int* __restrict__ csr_eid) {
    int e = blockIdx.x * 256 + threadIdx.x;
    if (e < N_EDGES) {
        int d = dst[e];
        int r = atomicAdd(&cursor[d], 1);
        int pos = offs[d] + r;
        csr_src[pos] = src[e];
        csr_eid[pos] = e;
    } else if (e < EN_TOT) {
        int n = e - N_EDGES;
        int pos = offs[n + 1] - 1;
        csr_src[pos] = n;
        csr_eid[pos] = N_EDGES + n;  // marker: self-loop
    }
}

// per-node mean of incoming edge attrs (self-loop attr), CSR-driven, no atomics
__global__ __launch_bounds__(256) void loopattr_csr(const int* __restrict__ offs,
                                                    const int* __restrict__ csr_eid,
                                                    const float* __restrict__ ea,
                                                    float* __restrict__ lattr) {
    int node = blockIdx.x * 4 + (threadIdx.x >> 6);
    if (node >= N_NODES) return;
    int lane = threadIdx.x & 63;
    int row = offs[node];
    int degn = offs[node + 1] - 1 - row;  // real edges only
    int k = lane & 15, grp = lane >> 4;
    float acc = 0.0f;
    for (int i = grp; i < degn; i += 4) {
        int eid = csr_eid[row + i];
        acc += ea[(long long)eid * EDGE_DIM + k];
    }
    acc += __shfl_xor(acc, 16);
    acc += __shfl_xor(acc, 32);
    if (lane < 16) lattr[(long long)node * EDGE_DIM + k] = acc / fmaxf((float)degn, 1.0f);
}

// ---------------- dense transforms ----------------
// out_l = in @ Wl.T + bl ; out_r = in @ Wr.T + br   (W: [128,K])
template<int K>
__global__ __launch_bounds__(256) void dual_linear(
    const float* __restrict__ in,
    const float* __restrict__ Wl, const float* __restrict__ bl,
    const float* __restrict__ Wr, const float* __restrict__ br,
    float* __restrict__ outl, float* __restrict__ outr, int N)
{
    constexpr int ROWS = 32;
    __shared__ float srow[ROWS][K];
    int t = threadIdx.x;
    int base = blockIdx.x * ROWS;
    for (int i = t; i < ROWS * K; i += 256) {
        int r = i / K, k = i - r * K;
        int n = base + r;
        srow[r][k] = (n < N) ? in[(long long)n * K + k] : 0.0f;
    }
    __syncthreads();
    const float* W  = (t < 128) ? Wl : Wr;
    const float* bb = (t < 128) ? bl : br;
    float* outp     = (t < 128) ? outl : outr;
    int j = t & 127;
    float bj = bb[j];
    float acc[ROWS];
#pragma unroll
    for (int r = 0; r < ROWS; ++r) acc[r] = bj;
    for (int k = 0; k < K; ++k) {
        float w = W[j * K + k];
#pragma unroll
        for (int r = 0; r < ROWS; ++r) acc[r] += srow[r][k] * w;
    }
    for (int r = 0; r < ROWS; ++r) {
        int n = base + r;
        if (n < N) outp[(long long)n * 128 + j] = acc[r];
    }
}

// ---------------- fused GATv2 (logits + online softmax + aggregation + bias [+ELU]) ----------------
// one wave per node; lane owns channels c0=lane, c1=lane+64
template<int DO_ELU>
__global__ __launch_bounds__(256) void gat_fused(
    const int* __restrict__ offs, const int* __restrict__ csr_src,
    const int* __restrict__ csr_eid,
    const float* __restrict__ ea, const float* __restrict__ lattr,
    const float* __restrict__ We, const float* __restrict__ att,
    const float* __restrict__ xl, const float* __restrict__ xr,
    const float* __restrict__ bias, float* __restrict__ y)
{
    int node = blockIdx.x * 4 + (threadIdx.x >> 6);
    if (node >= N_NODES) return;
    int lane = threadIdx.x & 63;
    int c0 = lane, c1 = lane + 64;

    float we0[EDGE_DIM], we1[EDGE_DIM];
#pragma unroll
    for (int k = 0; k < EDGE_DIM; ++k) {
        we0[k] = We[c0 * EDGE_DIM + k];
        we1[k] = We[c1 * EDGE_DIM + k];
    }
    float att0 = att[c0], att1 = att[c1];

    int row = offs[node], rend = offs[node + 1];
    float xr0 = xr[(long long)node * 128 + c0];
    float xr1 = xr[(long long)node * 128 + c1];

    float m0 = -INFINITY, m1 = -INFINITY;
    float d0 = 0.0f, d1 = 0.0f, acc0 = 0.0f, acc1 = 0.0f;

    // 1-deep prefetch of the csr entries to break the csr->gather latency chain
    int s_nxt = csr_src[row];
    int e_nxt = csr_eid[row];
    for (int i = row; i < rend; ++i) {
        int s = s_nxt, eid = e_nxt;
        if (i + 1 < rend) { s_nxt = csr_src[i + 1]; e_nxt = csr_eid[i + 1]; }

        const float* ap = (eid < N_EDGES) ? ea + (long long)eid * EDGE_DIM
                                          : lattr + (long long)(eid - N_EDGES) * EDGE_DIM;
        float av = (lane < EDGE_DIM) ? ap[lane] : 0.0f;
        float xls0 = xl[(long long)s * 128 + c0];
        float xls1 = xl[(long long)s * 128 + c1];

        float e0 = 0.0f, e1 = 0.0f;
#pragma unroll
        for (int k = 0; k < EDGE_DIM; ++k) {
            float ak = __shfl(av, k);
            e0 += ak * we0[k];
            e1 += ak * we1[k];
        }
        float v0 = xls0 + xr0 + e0, v1 = xls1 + xr1 + e1;
        v0 = (v0 > 0.0f) ? v0 : NEG_SLOPE * v0;
        v1 = (v1 > 0.0f) ? v1 : NEG_SLOPE * v1;
        float p0 = v0 * att0, p1 = v1 * att1;
#pragma unroll
        for (int off = 1; off <= 16; off <<= 1) {
            p0 += __shfl_xor(p0, off);
            p1 += __shfl_xor(p1, off);
        }
        // online softmax, stream 0 (head = lane>>5), stream 1 (head = 2 + (lane>>5))
        if (p0 > m0) { float r = __expf(m0 - p0); d0 *= r; acc0 *= r; m0 = p0; }
        float w0 = __expf(p0 - m0); d0 += w0; acc0 += w0 * xls0;
        if (p1 > m1) { float r = __expf(m1 - p1); d1 *= r; acc1 *= r; m1 = p1; }
        float w1 = __expf(p1 - m1); d1 += w1; acc1 += w1 * xls1;
    }

    float o0 = acc0 / d0 + bias[c0];
    float o1 = acc1 / d1 + bias[c1];
    if (DO_ELU) {
        o0 = (o0 > 0.0f) ? o0 : (__expf(o0) - 1.0f);
        o1 = (o1 > 0.0f) ? o1 : (__expf(o1) - 1.0f);
    }
    y[(long long)node * 128 + c0] = o0;
    y[(long long)node * 128 + c1] = o1;
}

// ---------------- pool (segmented reduction over sorted batch) + head ----------------
// 256 contiguous nodes per block; thread (c,h): channel c, nodes base+h, base+h+2, ...
// register-accumulate per batch run, flush on batch change (few atomics total).
__global__ __launch_bounds__(256) void pool_csr(const float* __restrict__ y,
                                                const int* __restrict__ batch,
                                                float* __restrict__ gsum,
                                                float* __restrict__ gcnt) {
    int base = blockIdx.x * 256;
    int t = threadIdx.x;
    int c = t & 127, h = t >> 7;
    int n = base + h;
    int end = min(base + 256, N_NODES);
    if (n >= end) return;
    float acc = 0.0f, cnt = 0.0f;
    int curb = batch[n];
    for (; n < end; n += 2) {
        int b = batch[n];
        if (b != curb) {
            atomicAdd(&gsum[curb * 128 + c], acc);
            if (c == 0) atomicAdd(&gcnt[curb], cnt);
            acc = 0.0f; cnt = 0.0f; curb = b;
        }
        acc += y[(long long)n * 128 + c];
        cnt += 1.0f;
    }
    atomicAdd(&gsum[curb * 128 + c], acc);
    if (c == 0) atomicAdd(&gcnt[curb], cnt);
}

__global__ __launch_bounds__(128) void head_kernel(
    const float* __restrict__ gsum, const float* __restrict__ gcnt,
    const float* __restrict__ Wg1, const float* __restrict__ bg1,
    const float* __restrict__ Wg2, const float* __restrict__ bg2,
    const float* __restrict__ Wp, const float* __restrict__ bp,
    float* __restrict__ out)
{
    int b = blockIdx.x;
    int j = threadIdx.x;
    __shared__ float g[128], h[128];
    float cntv = fmaxf(gcnt[b], 1.0f);
    g[j] = gsum[b * 128 + j] / cntv;
    __syncthreads();
    float a = bg1[j];
    for (int k = 0; k < 128; ++k) a += g[k] * Wg1[j * 128 + k];
    h[j] = fmaxf(a, 0.0f);
    __syncthreads();
    if (j < 15) {
        float o = bg2[j];
        for (int k = 0; k < 128; ++k) o += h[k] * Wg2[j * 128 + k];
        out[b * 25 + j] = o;
    }
    if (j >= 64 && j < 74) {
        int p = j - 64;
        float o = bp[p];
        for (int k = 0; k < 128; ++k) o += g[k] * Wp[p * 128 + k];
        out[b * 25 + 15 + p] = o;
    }
}

// ---------------- launch ----------------
extern "C" void kernel_launch(void* const* d_in, const int* in_sizes, int n_in,
                              void* d_out, int out_size, void* d_ws, size_t ws_size,
                              hipStream_t stream)
{
    const float* x     = (const float*)d_in[0];
    const int*   ei    = (const int*)  d_in[1];
    const float* ea    = (const float*)d_in[2];
    const int*   batch = (const int*)  d_in[3];
    const float* W1l = (const float*)d_in[4],  *b1l  = (const float*)d_in[5];
    const float* W1r = (const float*)d_in[6],  *b1r  = (const float*)d_in[7];
    const float* W1e = (const float*)d_in[8],  *att1 = (const float*)d_in[9];
    const float* bias1 = (const float*)d_in[10];
    const float* W2l = (const float*)d_in[11], *b2l  = (const float*)d_in[12];
    const float* W2r = (const float*)d_in[13], *b2r  = (const float*)d_in[14];
    const float* W2e = (const float*)d_in[15], *att2 = (const float*)d_in[16];
    const float* bias2 = (const float*)d_in[17];
    const float* Wg1 = (const float*)d_in[18], *bg1 = (const float*)d_in[19];
    const float* Wg2 = (const float*)d_in[20], *bg2 = (const float*)d_in[21];
    const float* Wp  = (const float*)d_in[22], *bp  = (const float*)d_in[23];
    const int* src = ei;
    const int* dst = ei + N_EDGES;

    // workspace layout (float units)
    float* ws = (float*)d_ws;
    size_t o = 0;
    float* xl    = ws + o; o += (size_t)N_NODES * 128;
    float* xr    = ws + o; o += (size_t)N_NODES * 128;
    float* y     = ws + o; o += (size_t)N_NODES * 128;
    float* lattr = ws + o; o += (size_t)N_NODES * EDGE_DIM;
    int* csr_src = (int*)(ws + o); o += (size_t)EN_TOT;
    int* csr_eid = (int*)(ws + o); o += (size_t)EN_TOT;
    int* offs    = (int*)(ws + o); o += (size_t)N_NODES + 1;
    int* deg     = (int*)(ws + o); o += (size_t)N_NODES;          // start of zero region
    int* cursor  = (int*)(ws + o); o += (size_t)N_NODES;
    float* gsum  = ws + o; o += (size_t)BATCH * 128;
    float* gcnt  = ws + o; o += (size_t)BATCH;                     // end of zero region
    int* bsum    = (int*)(ws + o); o += 512;
    int* incl    = (int*)y;  // scan temp, dead before y is written

    float* out = (float*)d_out;

    // zero deg, cursor, gsum, gcnt (contiguous)
    long long nz = (long long)N_NODES * 2 + BATCH * 128 + BATCH;
    zero_kernel<<<512, 256, 0, stream>>>((float*)deg, nz);

    // ---- CSR build (shared by both layers) ----
    count_deg<<<(N_EDGES + 255) / 256, 256, 0, stream>>>(dst, deg);
    scan1<<<NB_SCAN, 256, 0, stream>>>(deg, incl, bsum);
    scan2<<<1, 512, 0, stream>>>(bsum);
    scan3<<<NB_SCAN, 256, 0, stream>>>(incl, deg, bsum, offs);
    scatter<<<(EN_TOT + 255) / 256, 256, 0, stream>>>(src, dst, offs, cursor, csr_src, csr_eid);
    loopattr_csr<<<(N_NODES + 3) / 4, 256, 0, stream>>>(offs, csr_eid, ea, lattr);

    const int GAT_BLK = (N_NODES + 3) / 4;

    // ---- layer 1 ----
    dual_linear<32><<<(N_NODES + 31) / 32, 256, 0, stream>>>(x, W1l, b1l, W1r, b1r, xl, xr, N_NODES);
    gat_fused<1><<<GAT_BLK, 256, 0, stream>>>(offs, csr_src, csr_eid, ea, lattr,
                                              W1e, att1, xl, xr, bias1, y);

    // ---- layer 2 ----
    dual_linear<128><<<(N_NODES + 31) / 32, 256, 0, stream>>>(y, W2l, b2l, W2r, b2r, xl, xr, N_NODES);
    gat_fused<0><<<GAT_BLK, 256, 0, stream>>>(offs, csr_src, csr_eid, ea, lattr,
                                              W2e, att2, xl, xr, bias2, y);

    // ---- pool + head ----
    pool_csr<<<(N_NODES + 255) / 256, 256, 0, stream>>>(y, batch, gsum, gcnt);
    head_kernel<<<BATCH, 128, 0, stream>>>(gsum, gcnt, Wg1, bg1, Wg2, bg2, Wp, bp, out);
}